// Round 4
// baseline (643.829 us; speedup 1.0000x reference)
//
#include <hip/hip_runtime.h>
#include <stdint.h>

// B=4,H=8,Lq=512,NB=32,NT=128,D=64. Outputs: out [B,Lq,H*D] then attn_w [B,H,Lq,NB,NT].
// Structure: 1 wg = 16 q-rows x one (b,h); 4 waves; each wave owns 8 FULL n-blocks
// (per-block softmax -> fully in-wave, zero barriers in the main loop).
// R4: no XCD swizzle (8x L2 replication of K/V is a win; HBM has headroom),
//     P staged in LDS as f32 -> attn_w stored as full-line f32x4 (exact f32),
//     PV A-frag read back from f32 LDS + cvt_pkrtz.
constexpr int CB=4, CH=8, CLQ=512, CNB=32, CNT=128, CD=64;
constexpr int QT=16;      // q rows per workgroup
constexpr int PSTR=132;   // P LDS row stride (f32): mult of 4 (16B-aligned rows), stride%32=4 spreads banks
constexpr int OSTR=68;    // O reduce row stride (f32), inside each wave's P slice (1088 <= 2112 floats)

typedef __attribute__((ext_vector_type(8))) __fp16 half8;
typedef __attribute__((ext_vector_type(2))) __fp16 half2v;
typedef __attribute__((ext_vector_type(4))) float f32x4;

union HFrag { uint32_t u[4]; half8 h8; half2v h2[4]; };

__global__ __launch_bounds__(256, 4)
void sdpa_mfma_kernel(const float* __restrict__ qg, const float* __restrict__ kg,
                      const float* __restrict__ vg, const float* __restrict__ sg,
                      float* __restrict__ outg, float* __restrict__ awg)
{
    // per-wave P tile (16x128 f32, stride 132). After the loop each wave reuses ITS OWN
    // slice (same-wave WAR, no barrier) for the f32 O-reduction rows (stride 68).
    __shared__ __align__(16) float pbuf[4 * QT * PSTR];   // 33792 B
    __shared__ __align__(16) float as_t[CNB * QT];        // attn_s transposed [n][row], 2 KB

    const int tid  = threadIdx.x;
    const int wave = tid >> 6;
    const int lane = tid & 63;
    const int l15  = lane & 15;
    const int q8   = lane >> 4;

    const int bid = blockIdx.x;        // default round-robin across XCDs (no swizzle)
    const int qt  = bid & 31;
    const int bh  = bid >> 5;
    const int b   = bh >> 3;
    const int h   = bh & 7;
    const int q0  = qt * QT;

    // ---- stage attn_s transposed: as_t[n][r] ----
    {
        const float* sbase = sg + ((size_t)bh * CLQ + q0) * CNB;
        #pragma unroll
        for (int e = 0; e < 2; ++e) {
            int idx = tid + e * 256;          // 512 elems
            int r = idx >> 5, n = idx & 31;
            as_t[n * QT + r] = sbase[r * CNB + n];
        }
    }

    // ---- Q A-fragments (f16, persist): row = l15, k = s*32 + q8*8 + j ----
    HFrag qf[2];
    {
        const float* qrow = qg + ((size_t)bh * CLQ + q0 + l15) * CD;
        #pragma unroll
        for (int s = 0; s < 2; ++s) {
            f32x4 a = *(const f32x4*)&qrow[s*32 + q8*8];
            f32x4 c = *(const f32x4*)&qrow[s*32 + q8*8 + 4];
            qf[s].h2[0] = __builtin_amdgcn_cvt_pkrtz(a[0]*0.125f, a[1]*0.125f);
            qf[s].h2[1] = __builtin_amdgcn_cvt_pkrtz(a[2]*0.125f, a[3]*0.125f);
            qf[s].h2[2] = __builtin_amdgcn_cvt_pkrtz(c[0]*0.125f, c[1]*0.125f);
            qf[s].h2[3] = __builtin_amdgcn_cvt_pkrtz(c[2]*0.125f, c[3]*0.125f);
        }
    }

    f32x4 O[4];
    #pragma unroll
    for (int cd = 0; cd < 4; ++cd) O[cd] = (f32x4){0.f,0.f,0.f,0.f};

    float* pw = &pbuf[wave * QT * PSTR];

    __syncthreads();   // as_t ready — the ONLY barrier before the epilogue

    #pragma unroll 1
    for (int i = 0; i < 8; ++i) {
        const int n = (i << 2) | wave;      // each wave owns whole blocks
        const float* kb = kg + ((size_t)((b*CNB + n)*CH + h)) * CNT * CD;
        const float* vb = vg + ((size_t)((b*CNB + n)*CH + h)) * CNT * CD;

        // ---- QK^T over all 128 tokens: 8 c-tiles, f16 (K=64 -> 2 MFMA each) ----
        float Ev[8][4];                      // exp(S): [c][r], token = c*16+l15, row = q8*4+r
        #pragma unroll
        for (int c = 0; c < 8; ++c) {
            const float* kr = kb + (size_t)(c*16 + l15) * CD;
            HFrag kf[2];
            #pragma unroll
            for (int s = 0; s < 2; ++s) {
                f32x4 a = *(const f32x4*)&kr[s*32 + q8*8];
                f32x4 d = *(const f32x4*)&kr[s*32 + q8*8 + 4];
                kf[s].h2[0] = __builtin_amdgcn_cvt_pkrtz(a[0], a[1]);
                kf[s].h2[1] = __builtin_amdgcn_cvt_pkrtz(a[2], a[3]);
                kf[s].h2[2] = __builtin_amdgcn_cvt_pkrtz(d[0], d[1]);
                kf[s].h2[3] = __builtin_amdgcn_cvt_pkrtz(d[2], d[3]);
            }
            f32x4 acc = (f32x4){0.f,0.f,0.f,0.f};
            acc = __builtin_amdgcn_mfma_f32_16x16x32_f16(qf[0].h8, kf[0].h8, acc, 0, 0, 0);
            acc = __builtin_amdgcn_mfma_f32_16x16x32_f16(qf[1].h8, kf[1].h8, acc, 0, 0, 0);
            // no max-subtraction: |s| <~ 7, exp safe in fp32
            #pragma unroll
            for (int r = 0; r < 4; ++r) Ev[c][r] = __expf(acc[r]);
        }

        // ---- per-row softmax denominator, fully in-wave ----
        float ps[4];
        #pragma unroll
        for (int r = 0; r < 4; ++r)
            ps[r] = ((Ev[0][r]+Ev[1][r]) + (Ev[2][r]+Ev[3][r]))
                  + ((Ev[4][r]+Ev[5][r]) + (Ev[6][r]+Ev[7][r]));
        #pragma unroll
        for (int off = 1; off <= 8; off <<= 1) {
            #pragma unroll
            for (int r = 0; r < 4; ++r) ps[r] += __shfl_xor(ps[r], off, 64);
        }

        const f32x4 asv = *(const f32x4*)&as_t[n*QT + q8*4];
        float fac[4];
        #pragma unroll
        for (int r = 0; r < 4; ++r) fac[r] = asv[r] * __builtin_amdgcn_rcpf(ps[r]);

        // ---- P (exact f32) -> per-wave LDS tile ----
        #pragma unroll
        for (int r = 0; r < 4; ++r) {
            #pragma unroll
            for (int c = 0; c < 8; ++c)
                pw[(q8*4 + r)*PSTR + c*16 + l15] = Ev[c][r] * fac[r];
        }

        // ---- attn_w: full-line vectorized stores from LDS (same-wave, DS in-order) ----
        #pragma unroll
        for (int t = 0; t < 8; ++t) {
            int idx = lane + t*64;            // 512 f32x4 in the 16x128 tile
            int row = idx >> 5, c4 = idx & 31;
            f32x4 pv = *(const f32x4*)&pw[row*PSTR + c4*4];
            *(f32x4*)&awg[(((size_t)bh*CLQ + q0 + row)*CNB + n)*CNT + c4*4] = pv;
        }

        // ---- PV: A = P (f32 LDS read + pkrtz), B = V (scalar loads + pkrtz) ----
        #pragma unroll
        for (int ks = 0; ks < 4; ++ks) {
            f32x4 pa0 = *(const f32x4*)&pw[l15*PSTR + ks*32 + q8*8];
            f32x4 pa1 = *(const f32x4*)&pw[l15*PSTR + ks*32 + q8*8 + 4];
            HFrag pa;
            pa.h2[0] = __builtin_amdgcn_cvt_pkrtz(pa0[0], pa0[1]);
            pa.h2[1] = __builtin_amdgcn_cvt_pkrtz(pa0[2], pa0[3]);
            pa.h2[2] = __builtin_amdgcn_cvt_pkrtz(pa1[0], pa1[1]);
            pa.h2[3] = __builtin_amdgcn_cvt_pkrtz(pa1[2], pa1[3]);
            const float* vrow = vb + (size_t)(ks*32 + q8*8)*CD + l15;
            #pragma unroll
            for (int cd = 0; cd < 4; ++cd) {
                HFrag vf;
                #pragma unroll
                for (int p = 0; p < 4; ++p) {
                    float v0 = vrow[(2*p)*CD + cd*16];
                    float v1 = vrow[(2*p+1)*CD + cd*16];
                    vf.h2[p] = __builtin_amdgcn_cvt_pkrtz(v0, v1);
                }
                O[cd] = __builtin_amdgcn_mfma_f32_16x16x32_f16(pa.h8, vf.h8, O[cd], 0, 0, 0);
            }
        }
    }

    // ---- cross-wave O reduction (each wave's O rows live INSIDE its own P slice) ----
    {
        float* ow = pw;   // stride OSTR within the wave's 16*PSTR-float slice
        #pragma unroll
        for (int cd = 0; cd < 4; ++cd)
            #pragma unroll
            for (int r = 0; r < 4; ++r)
                ow[(q8*4 + r)*OSTR + cd*16 + l15] = O[cd][r];
    }
    __syncthreads();
    {
        int r = tid >> 4, dq = tid & 15;
        f32x4 acc = (f32x4){0.f,0.f,0.f,0.f};
        #pragma unroll
        for (int wv = 0; wv < 4; ++wv)
            acc += *(const f32x4*)&pbuf[wv*QT*PSTR + r*OSTR + dq*4];
        *(f32x4*)&outg[((size_t)b*CLQ + q0 + r)*(CH*CD) + h*CD + dq*4] = acc;
    }
}

extern "C" void kernel_launch(void* const* d_in, const int* in_sizes, int n_in,
                              void* d_out, int out_size, void* d_ws, size_t ws_size,
                              hipStream_t stream) {
    const float* q = (const float*)d_in[0];
    const float* k = (const float*)d_in[1];
    const float* v = (const float*)d_in[2];
    const float* s = (const float*)d_in[3];
    float* out = (float*)d_out;
    float* aw  = out + (size_t)CB * CLQ * CH * CD;

    const int grid = CB * CH * (CLQ / QT);   // 1024
    sdpa_mfma_kernel<<<grid, 256, 0, stream>>>(q, k, v, s, out, aw);
}

// Round 6
// 492.271 us; speedup vs baseline: 1.3079x; 1.3079x over previous
//
#include <hip/hip_runtime.h>
#include <stdint.h>

// B=4,H=8,Lq=512,NB=32,NT=128,D=64. Outputs: out [B,Lq,H*D] then attn_w [B,H,Lq,NB,NT].
// R5 = round-0 structure (proven 249us: n-loop, 4 waves share each n-block, 1 barrier/n)
// with ONLY the arithmetic swapped: f16 QK (2 MFMA, cvt_pkrtz) instead of bf16 hi/lo
// (6 MFMA + ~6x pack VALU), f16 PV packs, rcp instead of div.
constexpr int CB=4, CH=8, CLQ=512, CNB=32, CNT=128, CD=64;
constexpr int QT=16;      // q rows per workgroup (one MFMA M-tile)
constexpr int PSTR=36;    // P LDS row stride (f32)
constexpr int OSTR=68;    // O LDS row stride

typedef __attribute__((ext_vector_type(8))) __fp16 half8;
typedef __attribute__((ext_vector_type(2))) __fp16 half2v;
typedef __attribute__((ext_vector_type(4))) float f32x4;

union HFrag { uint32_t u[4]; half8 h8; half2v h2[4]; };

__global__ __launch_bounds__(256, 4)
void sdpa_mfma_kernel(const float* __restrict__ qg, const float* __restrict__ kg,
                      const float* __restrict__ vg, const float* __restrict__ sg,
                      float* __restrict__ outg, float* __restrict__ awg)
{
    __shared__ __align__(16) float pbuf[4 * QT * PSTR];   // per-wave P tile (16x32 f32)
    __shared__ __align__(16) float sums[2][64];           // row-sum partials, double-buffered
    __shared__ __align__(16) float as_t[CNB * QT];        // attn_s transposed [n][row]
    __shared__ __align__(16) float obuf[4 * QT * OSTR];   // cross-wave O reduction

    const int tid  = threadIdx.x;
    const int wave = tid >> 6;
    const int lane = tid & 63;
    const int l15  = lane & 15;
    const int q8   = lane >> 4;

    const int bid = blockIdx.x;       // bh*32 + qtile (no swizzle — round-0 proven)
    const int qt  = bid & 31;
    const int bh  = bid >> 5;
    const int b   = bh >> 3;
    const int h   = bh & 7;
    const int q0  = qt * QT;

    // ---- stage attn_s transposed: as_t[n][r] ----
    {
        const float* sbase = sg + ((size_t)bh * CLQ + q0) * CNB;
        #pragma unroll
        for (int e = 0; e < 2; ++e) {
            int idx = tid + e * 256;          // 512 elems
            int r = idx >> 5, n = idx & 31;
            as_t[n * QT + r] = sbase[r * CNB + n];
        }
    }

    // ---- Q A-fragments (f16, persist): q row = l15, k = s*32 + q8*8 + j ----
    HFrag qf[2];
    {
        const float* qrow = qg + ((size_t)bh * CLQ + q0 + l15) * CD;
        #pragma unroll
        for (int s = 0; s < 2; ++s) {
            f32x4 a = *(const f32x4*)&qrow[s*32 + q8*8];
            f32x4 c = *(const f32x4*)&qrow[s*32 + q8*8 + 4];
            qf[s].h2[0] = __builtin_amdgcn_cvt_pkrtz(a[0]*0.125f, a[1]*0.125f);
            qf[s].h2[1] = __builtin_amdgcn_cvt_pkrtz(a[2]*0.125f, a[3]*0.125f);
            qf[s].h2[2] = __builtin_amdgcn_cvt_pkrtz(c[0]*0.125f, c[1]*0.125f);
            qf[s].h2[3] = __builtin_amdgcn_cvt_pkrtz(c[2]*0.125f, c[3]*0.125f);
        }
    }

    f32x4 O[4];
    #pragma unroll
    for (int cd = 0; cd < 4; ++cd) O[cd] = (f32x4){0.f,0.f,0.f,0.f};

    float* pw = &pbuf[wave * QT * PSTR];

    for (int n = 0; n < CNB; ++n) {
        const float* kb = kg + ((size_t)((b*CNB + n)*CH + h)) * CNT * CD;
        const float* vb = vg + ((size_t)((b*CNB + n)*CH + h)) * CNT * CD + wave*32*CD;

        // ---- QK^T scores for this wave's 32 tokens: f16, 2 MFMA per 16-token tile ----
        f32x4 S[2];
        #pragma unroll
        for (int c = 0; c < 2; ++c) {
            const float* kr = kb + (size_t)(wave*32 + c*16 + l15) * CD;
            HFrag kf[2];
            #pragma unroll
            for (int s = 0; s < 2; ++s) {
                f32x4 a = *(const f32x4*)&kr[s*32 + q8*8];
                f32x4 d = *(const f32x4*)&kr[s*32 + q8*8 + 4];
                kf[s].h2[0] = __builtin_amdgcn_cvt_pkrtz(a[0], a[1]);
                kf[s].h2[1] = __builtin_amdgcn_cvt_pkrtz(a[2], a[3]);
                kf[s].h2[2] = __builtin_amdgcn_cvt_pkrtz(d[0], d[1]);
                kf[s].h2[3] = __builtin_amdgcn_cvt_pkrtz(d[2], d[3]);
            }
            f32x4 acc = (f32x4){0.f,0.f,0.f,0.f};
            acc = __builtin_amdgcn_mfma_f32_16x16x32_f16(qf[0].h8, kf[0].h8, acc, 0, 0, 0);
            acc = __builtin_amdgcn_mfma_f32_16x16x32_f16(qf[1].h8, kf[1].h8, acc, 0, 0, 0);
            S[c] = acc;
        }

        // ---- softmax denominator (no max-sub: |s| <~ 7, exp safe in fp32) ----
        float E0[4], E1[4], ps[4];
        #pragma unroll
        for (int r = 0; r < 4; ++r) {
            E0[r] = __expf(S[0][r]);
            E1[r] = __expf(S[1][r]);
            ps[r] = E0[r] + E1[r];
        }
        #pragma unroll
        for (int off = 1; off <= 8; off <<= 1) {
            #pragma unroll
            for (int r = 0; r < 4; ++r) ps[r] += __shfl_xor(ps[r], off, 64);
        }
        if (l15 == 0) {
            f32x4 t = {ps[0], ps[1], ps[2], ps[3]};
            *(f32x4*)&sums[n & 1][wave*16 + q8*4] = t;
        }
        __syncthreads();

        f32x4 d4 = (f32x4){0.f,0.f,0.f,0.f};
        #pragma unroll
        for (int wv = 0; wv < 4; ++wv)
            d4 += *(const f32x4*)&sums[n & 1][wv*16 + q8*4];
        const f32x4 asv = *(const f32x4*)&as_t[n*QT + q8*4];

        float fac[4];
        #pragma unroll
        for (int r = 0; r < 4; ++r) fac[r] = asv[r] * __builtin_amdgcn_rcpf(d4[r]);

        // ---- P = exp * attn_s / denom -> per-wave LDS tile (C-layout write) ----
        #pragma unroll
        for (int r = 0; r < 4; ++r) {
            pw[(q8*4 + r)*PSTR + l15]      = E0[r] * fac[r];
            pw[(q8*4 + r)*PSTR + 16 + l15] = E1[r] * fac[r];
        }

        // ---- attn_w coalesced store from LDS ----
        #pragma unroll
        for (int i = 0; i < 2; ++i) {
            int idx = lane + i*64;           // 128 float4s in 16x32 tile
            int row = idx >> 3, c4 = idx & 7;
            f32x4 pv = *(const f32x4*)&pw[row*PSTR + c4*4];
            *(f32x4*)&awg[(((size_t)bh*CLQ + q0 + row)*CNB + n)*CNT + wave*32 + c4*4] = pv;
        }

        // ---- P in A-layout (row=l15, k=q8*8+j), f16 via pkrtz ----
        HFrag pa;
        {
            f32x4 a = *(const f32x4*)&pw[l15*PSTR + q8*8];
            f32x4 c = *(const f32x4*)&pw[l15*PSTR + q8*8 + 4];
            pa.h2[0] = __builtin_amdgcn_cvt_pkrtz(a[0], a[1]);
            pa.h2[1] = __builtin_amdgcn_cvt_pkrtz(a[2], a[3]);
            pa.h2[2] = __builtin_amdgcn_cvt_pkrtz(c[0], c[1]);
            pa.h2[3] = __builtin_amdgcn_cvt_pkrtz(c[2], c[3]);
        }

        // ---- PV: B-frag = V[t0 + q8*8 + j][cd*16 + l15], O += P*V ----
        #pragma unroll
        for (int cd = 0; cd < 4; ++cd) {
            float vf[8];
            #pragma unroll
            for (int j = 0; j < 8; ++j)
                vf[j] = vb[(q8*8 + j)*CD + cd*16 + l15];
            HFrag vh;
            #pragma unroll
            for (int p = 0; p < 4; ++p)
                vh.h2[p] = __builtin_amdgcn_cvt_pkrtz(vf[2*p], vf[2*p+1]);
            O[cd] = __builtin_amdgcn_mfma_f32_16x16x32_f16(pa.h8, vh.h8, O[cd], 0, 0, 0);
        }
    }

    // ---- cross-wave O reduction ----
    {
        float* ow = &obuf[wave * QT * OSTR];
        #pragma unroll
        for (int cd = 0; cd < 4; ++cd)
            #pragma unroll
            for (int r = 0; r < 4; ++r)
                ow[(q8*4 + r)*OSTR + cd*16 + l15] = O[cd][r];
    }
    __syncthreads();
    {
        int r = tid >> 4, dq = tid & 15;
        f32x4 acc = (f32x4){0.f,0.f,0.f,0.f};
        #pragma unroll
        for (int wv = 0; wv < 4; ++wv)
            acc += *(const f32x4*)&obuf[wv*QT*OSTR + r*OSTR + dq*4];
        *(f32x4*)&outg[((size_t)b*CLQ + q0 + r)*(CH*CD) + h*CD + dq*4] = acc;
    }
}

extern "C" void kernel_launch(void* const* d_in, const int* in_sizes, int n_in,
                              void* d_out, int out_size, void* d_ws, size_t ws_size,
                              hipStream_t stream) {
    const float* q = (const float*)d_in[0];
    const float* k = (const float*)d_in[1];
    const float* v = (const float*)d_in[2];
    const float* s = (const float*)d_in[3];
    float* out = (float*)d_out;
    float* aw  = out + (size_t)CB * CLQ * CH * CD;

    const int grid = CB * CH * (CLQ / QT);   // 1024
    sdpa_mfma_kernel<<<grid, 256, 0, stream>>>(q, k, v, s, out, aw);
}